// Round 1
// baseline (313.324 us; speedup 1.0000x reference)
//
#include <hip/hip_runtime.h>

#define BB 32
#define TT 1024
#define ENCD 1024
#define DECD 1024
#define MELD 80
#define KTOT (MELD + ENCD + DECD)   // 2128
#define NZ (4 * DECD)               // 4096
#define KCH 64                      // k-rows per zmm chunk
#define KC 34                       // ceil(2128/64); last chunk = 16 rows
#define NTT 32                      // context t-chunks (32 rows each)

// ---- static device scratch ----
__device__ float g_cp[NTT * BB * ENCD];  // context partials [tt][b][d] (4 MB)
__device__ float g_m[NTT * BB];          // per-chunk running max
__device__ float g_s[NTT * BB];          // per-chunk exp-sum (at that max)
__device__ float g_ctx[BB * ENCD];
__device__ float g_zp[KC * BB * NZ];     // z partials [kc][b][j] (17.8 MB)
__device__ float g_hn[BB * DECD];

__device__ __forceinline__ float tanh_fast(float x) {
    // 1 - 2/(e+1): exact +-1 limits (rcp(inf)=0)
    return 1.f - __fdividef(2.f, __expf(2.f * x) + 1.f);
}
__device__ __forceinline__ float sigmoid_fast(float x) {
    return __fdividef(1.f, 1.f + __expf(-x));
}

// ---------------------------------------------------------------------------
// K1: fused flash-style attention partials. ONE pass over enc (was two).
// grid (b=32, tc=32), 256 threads = 4 waves; wave w handles 8 t-rows.
// Per t: load enc row into regs (4xfloat4/lane), score = sum scale*tanh(h+e),
// butterfly-reduce (all lanes get score), online-softmax update of
// (m, s, ctx[16]) in registers. Block-combine 4 wave partials via LDS,
// write g_cp[tc][b][:], g_m/g_s[tc][b].
// ---------------------------------------------------------------------------
__global__ __launch_bounds__(256) void k_attn(const float* __restrict__ enc,
                                              const float* __restrict__ hst,
                                              const float* __restrict__ scale) {
    int b = blockIdx.x, tc = blockIdx.y;
    int w = threadIdx.x >> 6, lane = threadIdx.x & 63;
    const float4* hp = (const float4*)(hst + (size_t)b * DECD);
    const float4* sp = (const float4*)scale;
    float4 hr0 = hp[lane], hr1 = hp[lane + 64], hr2 = hp[lane + 128], hr3 = hp[lane + 192];
    float4 sr0 = sp[lane], sr1 = sp[lane + 64], sr2 = sp[lane + 128], sr3 = sp[lane + 192];

    float m = -1e30f, s = 0.f;
    float4 c0 = {0.f, 0.f, 0.f, 0.f}, c1 = c0, c2 = c0, c3 = c0;

    const float4* ep = (const float4*)(enc + ((size_t)b * TT + tc * 32 + w * 8) * ENCD) + lane;
#pragma unroll 2
    for (int t = 0; t < 8; t++) {
        float4 e0 = ep[t * 256];
        float4 e1 = ep[t * 256 + 64];
        float4 e2 = ep[t * 256 + 128];
        float4 e3 = ep[t * 256 + 192];
        float sc = 0.f;
        sc = fmaf(sr0.x, tanh_fast(hr0.x + e0.x), sc);
        sc = fmaf(sr0.y, tanh_fast(hr0.y + e0.y), sc);
        sc = fmaf(sr0.z, tanh_fast(hr0.z + e0.z), sc);
        sc = fmaf(sr0.w, tanh_fast(hr0.w + e0.w), sc);
        sc = fmaf(sr1.x, tanh_fast(hr1.x + e1.x), sc);
        sc = fmaf(sr1.y, tanh_fast(hr1.y + e1.y), sc);
        sc = fmaf(sr1.z, tanh_fast(hr1.z + e1.z), sc);
        sc = fmaf(sr1.w, tanh_fast(hr1.w + e1.w), sc);
        sc = fmaf(sr2.x, tanh_fast(hr2.x + e2.x), sc);
        sc = fmaf(sr2.y, tanh_fast(hr2.y + e2.y), sc);
        sc = fmaf(sr2.z, tanh_fast(hr2.z + e2.z), sc);
        sc = fmaf(sr2.w, tanh_fast(hr2.w + e2.w), sc);
        sc = fmaf(sr3.x, tanh_fast(hr3.x + e3.x), sc);
        sc = fmaf(sr3.y, tanh_fast(hr3.y + e3.y), sc);
        sc = fmaf(sr3.z, tanh_fast(hr3.z + e3.z), sc);
        sc = fmaf(sr3.w, tanh_fast(hr3.w + e3.w), sc);
#pragma unroll
        for (int off = 32; off; off >>= 1) sc += __shfl_xor(sc, off, 64);
        if (sc > m) {           // wave-uniform branch: sc identical in all lanes
            float al = __expf(m - sc);   // first iter: exp(-1e30-sc) -> 0
            s = fmaf(s, al, 1.f);
            c0.x = fmaf(c0.x, al, e0.x); c0.y = fmaf(c0.y, al, e0.y);
            c0.z = fmaf(c0.z, al, e0.z); c0.w = fmaf(c0.w, al, e0.w);
            c1.x = fmaf(c1.x, al, e1.x); c1.y = fmaf(c1.y, al, e1.y);
            c1.z = fmaf(c1.z, al, e1.z); c1.w = fmaf(c1.w, al, e1.w);
            c2.x = fmaf(c2.x, al, e2.x); c2.y = fmaf(c2.y, al, e2.y);
            c2.z = fmaf(c2.z, al, e2.z); c2.w = fmaf(c2.w, al, e2.w);
            c3.x = fmaf(c3.x, al, e3.x); c3.y = fmaf(c3.y, al, e3.y);
            c3.z = fmaf(c3.z, al, e3.z); c3.w = fmaf(c3.w, al, e3.w);
            m = sc;
        } else {
            float p = __expf(sc - m);
            s += p;
            c0.x = fmaf(p, e0.x, c0.x); c0.y = fmaf(p, e0.y, c0.y);
            c0.z = fmaf(p, e0.z, c0.z); c0.w = fmaf(p, e0.w, c0.w);
            c1.x = fmaf(p, e1.x, c1.x); c1.y = fmaf(p, e1.y, c1.y);
            c1.z = fmaf(p, e1.z, c1.z); c1.w = fmaf(p, e1.w, c1.w);
            c2.x = fmaf(p, e2.x, c2.x); c2.y = fmaf(p, e2.y, c2.y);
            c2.z = fmaf(p, e2.z, c2.z); c2.w = fmaf(p, e2.w, c2.w);
            c3.x = fmaf(p, e3.x, c3.x); c3.y = fmaf(p, e3.y, c3.y);
            c3.z = fmaf(p, e3.z, c3.z); c3.w = fmaf(p, e3.w, c3.w);
        }
    }

    // ---- block combine: 4 wave partials -> one chunk partial ----
    __shared__ float lm[4], ls[4];
    __shared__ float4 lctx[4][256];
    if (lane == 0) { lm[w] = m; ls[w] = s; }
    __syncthreads();
    float M = fmaxf(fmaxf(lm[0], lm[1]), fmaxf(lm[2], lm[3]));
    float S = ls[0] * __expf(lm[0] - M) + ls[1] * __expf(lm[1] - M) +
              ls[2] * __expf(lm[2] - M) + ls[3] * __expf(lm[3] - M);
    float be = __expf(m - M);
    float4 o;
    o.x = c0.x * be; o.y = c0.y * be; o.z = c0.z * be; o.w = c0.w * be;
    lctx[w][lane] = o;
    o.x = c1.x * be; o.y = c1.y * be; o.z = c1.z * be; o.w = c1.w * be;
    lctx[w][lane + 64] = o;
    o.x = c2.x * be; o.y = c2.y * be; o.z = c2.z * be; o.w = c2.w * be;
    lctx[w][lane + 128] = o;
    o.x = c3.x * be; o.y = c3.y * be; o.z = c3.z * be; o.w = c3.w * be;
    lctx[w][lane + 192] = o;
    __syncthreads();
    int tid = threadIdx.x;
    float4 a0 = lctx[0][tid], a1 = lctx[1][tid], a2 = lctx[2][tid], a3 = lctx[3][tid];
    float4 r;
    r.x = (a0.x + a1.x) + (a2.x + a3.x);
    r.y = (a0.y + a1.y) + (a2.y + a3.y);
    r.z = (a0.z + a1.z) + (a2.z + a3.z);
    r.w = (a0.w + a1.w) + (a2.w + a3.w);
    ((float4*)g_cp)[((size_t)tc * BB + b) * (ENCD / 4) + tid] = r;
    if (tid == 0) { g_m[tc * BB + b] = M; g_s[tc * BB + b] = S; }
}

// ---------------------------------------------------------------------------
// K2: combine 32 chunk partials per batch with global max/sum correction.
// grid 32 (b); thread owns one float4 of the 1024-d context row.
// ---------------------------------------------------------------------------
__global__ __launch_bounds__(256) void k_combine() {
    __shared__ float wgt[NTT];
    int b = blockIdx.x, tid = threadIdx.x;
    float M = -1e30f;
#pragma unroll
    for (int tt = 0; tt < NTT; tt++) M = fmaxf(M, g_m[tt * BB + b]);
    float S = 0.f;
#pragma unroll
    for (int tt = 0; tt < NTT; tt++) S += g_s[tt * BB + b] * __expf(g_m[tt * BB + b] - M);
    if (tid < NTT) wgt[tid] = __expf(g_m[tid * BB + b] - M) * __fdividef(1.f, S);
    __syncthreads();
    const float4* cp = (const float4*)g_cp + (size_t)b * (ENCD / 4) + tid;
    float ax = 0.f, ay = 0.f, az = 0.f, aw = 0.f;
#pragma unroll 8
    for (int tt = 0; tt < NTT; tt++) {
        float4 v = cp[(size_t)tt * (BB * ENCD / 4)];
        float wv = wgt[tt];
        ax = fmaf(wv, v.x, ax); ay = fmaf(wv, v.y, ay);
        az = fmaf(wv, v.z, az); aw = fmaf(wv, v.w, aw);
    }
    float4 r; r.x = ax; r.y = ay; r.z = az; r.w = aw;
    ((float4*)g_ctx)[b * (ENCD / 4) + tid] = r;
}

// ---------------------------------------------------------------------------
// K3: z partials. grid 544 = 16 jt x 34 kc (KCH=64; last chunk 16 rows).
// x staged in LDS for all 32 batches; weight loads batched 8-wide.
// ---------------------------------------------------------------------------
__global__ __launch_bounds__(256) void k_zmm(const float* __restrict__ pm,
                                             const float* __restrict__ h,
                                             const float* __restrict__ kern,
                                             const float* __restrict__ reck) {
    __shared__ float xs[KCH * 32];
    int jt = blockIdx.x & 15, kc = blockIdx.x >> 4;
    int k0 = kc * KCH;
    int kcount = min(KCH, KTOT - k0);   // 64 or 16, both divisible by 8
    int tid = threadIdx.x;
    for (int idx = tid; idx < kcount * 32; idx += 256) {
        int kk = idx >> 5, b = idx & 31;
        int k = k0 + kk;
        float v;
        if (k < MELD)             v = pm[b * MELD + k];
        else if (k < MELD + ENCD) v = g_ctx[b * ENCD + (k - MELD)];
        else                      v = h[b * DECD + (k - MELD - ENCD)];
        xs[idx] = v;
    }
    __syncthreads();
    int j = jt * 256 + tid;
    float acc[32];
#pragma unroll
    for (int b = 0; b < 32; b++) acc[b] = 0.f;
    for (int kk0 = 0; kk0 < kcount; kk0 += 8) {
        float w[8];
#pragma unroll
        for (int i = 0; i < 8; i++) {
            int k = k0 + kk0 + i;
            w[i] = (k < MELD + ENCD) ? kern[(size_t)k * NZ + j]
                                     : reck[(size_t)(k - MELD - ENCD) * NZ + j];
        }
#pragma unroll
        for (int i = 0; i < 8; i++) {
            const float* xr = xs + (kk0 + i) * 32;
#pragma unroll
            for (int b = 0; b < 32; b++) acc[b] = fmaf(xr[b], w[i], acc[b]);
        }
    }
#pragma unroll
    for (int b = 0; b < 32; b++) g_zp[((size_t)kc * BB + b) * NZ + j] = acc[b];
}

// ---------------------------------------------------------------------------
// K4: sum z partials + bias, gates -> h_new/c_new (fp32 out).
// grid 512 = 32 b x 16 jt (j-tile 64); kc-sum split 4-way across thread
// groups, LDS reduce. out: mel[0,2560) h[2560,35328) c[35328,68096)
// ---------------------------------------------------------------------------
__global__ __launch_bounds__(256) void k_gates(const float* __restrict__ bias,
                                               const float* __restrict__ c,
                                               float* __restrict__ out) {
    __shared__ float sacc[4][4][64];   // [grp][gate][jl]
    int b = blockIdx.x >> 4, jq = blockIdx.x & 15;
    int jl = threadIdx.x & 63, grp = threadIdx.x >> 6;
    int j = jq * 64 + jl;
    // kc ranges per group: 9,9,9,7
    int kc0 = grp * 9;
    int kc1 = min(kc0 + 9, KC);
    float zi = 0.f, zf = 0.f, zg = 0.f, zo = 0.f;
    for (int kc = kc0; kc < kc1; kc++) {
        const float* zp = g_zp + ((size_t)kc * BB + b) * NZ;
        zi += zp[j];
        zf += zp[1024 + j];
        zg += zp[2048 + j];
        zo += zp[3072 + j];
    }
    sacc[grp][0][jl] = zi; sacc[grp][1][jl] = zf;
    sacc[grp][2][jl] = zg; sacc[grp][3][jl] = zo;
    __syncthreads();
    if (grp == 0) {
        zi = sacc[0][0][jl] + sacc[1][0][jl] + sacc[2][0][jl] + sacc[3][0][jl] + bias[j];
        zf = sacc[0][1][jl] + sacc[1][1][jl] + sacc[2][1][jl] + sacc[3][1][jl] + bias[1024 + j];
        zg = sacc[0][2][jl] + sacc[1][2][jl] + sacc[2][2][jl] + sacc[3][2][jl] + bias[2048 + j];
        zo = sacc[0][3][jl] + sacc[1][3][jl] + sacc[2][3][jl] + sacc[3][3][jl] + bias[3072 + j];
        int idx = b * 1024 + j;
        float cn = sigmoid_fast(zf) * c[idx] + sigmoid_fast(zi) * tanh_fast(zg);
        float hn = sigmoid_fast(zo) * tanh_fast(cn);
        g_hn[idx] = hn;
        out[2560 + idx] = hn;
        out[35328 + idx] = cn;
    }
}

// ---------------------------------------------------------------------------
// K5: mel[b,m] = h_new[b,:] @ proj_w[:,m] + proj_b[m]
// grid 32; 160 active threads = 80 m x 2 d-halves, LDS combine.
// ---------------------------------------------------------------------------
__global__ __launch_bounds__(256) void k_proj(const float* __restrict__ pw,
                                              const float* __restrict__ pb,
                                              float* __restrict__ out) {
    __shared__ float lh[1024];
    __shared__ float pacc[2][MELD];
    int b = blockIdx.x, tid = threadIdx.x;
    for (int i = tid; i < 1024; i += 256) lh[i] = g_hn[b * 1024 + i];
    __syncthreads();
    int m = tid & 127;
    int g = tid >> 7;
    if (m < MELD) {
        float acc = 0.f;
        int d0 = g * 512;
#pragma unroll 8
        for (int d = d0; d < d0 + 512; d++) acc = fmaf(lh[d], pw[d * MELD + m], acc);
        pacc[g][m] = acc;
    }
    __syncthreads();
    if (tid < MELD) out[b * MELD + tid] = pacc[0][tid] + pacc[1][tid] + pb[tid];
}

extern "C" void kernel_launch(void* const* d_in, const int* in_sizes, int n_in,
                              void* d_out, int out_size, void* d_ws, size_t ws_size,
                              hipStream_t stream) {
    const float* pm   = (const float*)d_in[0];   // prev_mel_frame [32,80]
    const float* enc  = (const float*)d_in[1];   // encoder_outputs [32,1024,1024]
    const float* h    = (const float*)d_in[2];   // h [32,1024]
    const float* c    = (const float*)d_in[3];   // c [32,1024]
    const float* asc  = (const float*)d_in[4];   // attn_scale [1024]
    const float* kern = (const float*)d_in[5];   // kernel [1104,4096]
    const float* reck = (const float*)d_in[6];   // rec_kernel [1024,4096]
    const float* bias = (const float*)d_in[7];   // bias [4096]
    const float* pw   = (const float*)d_in[8];   // proj_w [1024,80]
    const float* pb   = (const float*)d_in[9];   // proj_b [80]
    float* out = (float*)d_out;                  // fp32: mel | h_new | c_new

    k_attn   <<<dim3(32, NTT), 256, 0, stream>>>(enc, h, asc);
    k_combine<<<32, 256, 0, stream>>>();
    k_zmm    <<<544, 256, 0, stream>>>(pm, h, kern, reck);
    k_gates  <<<512, 256, 0, stream>>>(bias, c, out);
    k_proj   <<<32, 256, 0, stream>>>(pw, pb, out);
}

// Round 2
// 306.890 us; speedup vs baseline: 1.0210x; 1.0210x over previous
//
#include <hip/hip_runtime.h>

#define BB 32
#define TT 1024
#define ENCD 1024
#define DECD 1024
#define MELD 80
#define KTOT (MELD + ENCD + DECD)   // 2128
#define NZ (4 * DECD)               // 4096
#define KCH 128                     // k-rows per zmm chunk
#define KC 17                       // ceil(2128/128); last chunk = 80 rows
#define NTT 32                      // context t-chunks (32 rows each)

// ---- static device scratch ----
__device__ float g_cp[NTT * BB * ENCD];  // context partials [tt][b][d] (4 MB)
__device__ float g_m[NTT * BB];          // per-chunk running max
__device__ float g_s[NTT * BB];          // per-chunk exp-sum (at that max)
__device__ float g_ctx[BB * ENCD];
__device__ float g_zp[KC * BB * NZ];     // z partials [kc][b][j] (8.9 MB)
__device__ float g_hn[BB * DECD];

__device__ __forceinline__ float tanh_fast(float x) {
    // 1 - 2/(e+1): exact +-1 limits (rcp(inf)=0)
    return 1.f - __fdividef(2.f, __expf(2.f * x) + 1.f);
}
__device__ __forceinline__ float sigmoid_fast(float x) {
    return __fdividef(1.f, 1.f + __expf(-x));
}

// ---------------------------------------------------------------------------
// K1: fused flash-style attention partials, ONE pass over enc.
// grid (b=32, tc=32) = 1024 blocks (exactly 4/CU), 256 thr = 4 waves,
// wave w owns 8 t-rows. BRANCHLESS online softmax (mn/al/p form) so the
// compiler can pipeline next-row loads past the update — the round-1
// `if (sc>m)` branch blocked load hoisting and serialized HBM latency.
// ---------------------------------------------------------------------------
__global__ __launch_bounds__(256, 4) void k_attn(const float* __restrict__ enc,
                                                 const float* __restrict__ hst,
                                                 const float* __restrict__ scale) {
    int b = blockIdx.x, tc = blockIdx.y;
    int w = threadIdx.x >> 6, lane = threadIdx.x & 63;
    const float4* hp = (const float4*)(hst + (size_t)b * DECD);
    const float4* sp = (const float4*)scale;
    float4 hr0 = hp[lane], hr1 = hp[lane + 64], hr2 = hp[lane + 128], hr3 = hp[lane + 192];
    float4 sr0 = sp[lane], sr1 = sp[lane + 64], sr2 = sp[lane + 128], sr3 = sp[lane + 192];

    float m = -1e30f, s = 0.f;
    float4 c0 = {0.f, 0.f, 0.f, 0.f}, c1 = c0, c2 = c0, c3 = c0;

    const float4* ep = (const float4*)(enc + ((size_t)b * TT + tc * 32 + w * 8) * ENCD) + lane;
#pragma unroll 2
    for (int t = 0; t < 8; t++) {
        float4 e0 = ep[t * 256];
        float4 e1 = ep[t * 256 + 64];
        float4 e2 = ep[t * 256 + 128];
        float4 e3 = ep[t * 256 + 192];
        float sc = 0.f;
        sc = fmaf(sr0.x, tanh_fast(hr0.x + e0.x), sc);
        sc = fmaf(sr0.y, tanh_fast(hr0.y + e0.y), sc);
        sc = fmaf(sr0.z, tanh_fast(hr0.z + e0.z), sc);
        sc = fmaf(sr0.w, tanh_fast(hr0.w + e0.w), sc);
        sc = fmaf(sr1.x, tanh_fast(hr1.x + e1.x), sc);
        sc = fmaf(sr1.y, tanh_fast(hr1.y + e1.y), sc);
        sc = fmaf(sr1.z, tanh_fast(hr1.z + e1.z), sc);
        sc = fmaf(sr1.w, tanh_fast(hr1.w + e1.w), sc);
        sc = fmaf(sr2.x, tanh_fast(hr2.x + e2.x), sc);
        sc = fmaf(sr2.y, tanh_fast(hr2.y + e2.y), sc);
        sc = fmaf(sr2.z, tanh_fast(hr2.z + e2.z), sc);
        sc = fmaf(sr2.w, tanh_fast(hr2.w + e2.w), sc);
        sc = fmaf(sr3.x, tanh_fast(hr3.x + e3.x), sc);
        sc = fmaf(sr3.y, tanh_fast(hr3.y + e3.y), sc);
        sc = fmaf(sr3.z, tanh_fast(hr3.z + e3.z), sc);
        sc = fmaf(sr3.w, tanh_fast(hr3.w + e3.w), sc);
#pragma unroll
        for (int off = 32; off; off >>= 1) sc += __shfl_xor(sc, off, 64);
        // branchless online-softmax update (wave-uniform sc)
        float mn = fmaxf(m, sc);
        float al = __expf(m - mn);    // first iter: exp(-inf) = 0
        float p  = __expf(sc - mn);
        m = mn;
        s = fmaf(s, al, p);
        c0.x = fmaf(p, e0.x, c0.x * al); c0.y = fmaf(p, e0.y, c0.y * al);
        c0.z = fmaf(p, e0.z, c0.z * al); c0.w = fmaf(p, e0.w, c0.w * al);
        c1.x = fmaf(p, e1.x, c1.x * al); c1.y = fmaf(p, e1.y, c1.y * al);
        c1.z = fmaf(p, e1.z, c1.z * al); c1.w = fmaf(p, e1.w, c1.w * al);
        c2.x = fmaf(p, e2.x, c2.x * al); c2.y = fmaf(p, e2.y, c2.y * al);
        c2.z = fmaf(p, e2.z, c2.z * al); c2.w = fmaf(p, e2.w, c2.w * al);
        c3.x = fmaf(p, e3.x, c3.x * al); c3.y = fmaf(p, e3.y, c3.y * al);
        c3.z = fmaf(p, e3.z, c3.z * al); c3.w = fmaf(p, e3.w, c3.w * al);
    }

    // ---- block combine: 4 wave partials -> one chunk partial ----
    __shared__ float lm[4], ls[4];
    __shared__ float4 lctx[4][256];
    if (lane == 0) { lm[w] = m; ls[w] = s; }
    __syncthreads();
    float M = fmaxf(fmaxf(lm[0], lm[1]), fmaxf(lm[2], lm[3]));
    float S = ls[0] * __expf(lm[0] - M) + ls[1] * __expf(lm[1] - M) +
              ls[2] * __expf(lm[2] - M) + ls[3] * __expf(lm[3] - M);
    float be = __expf(m - M);
    float4 o;
    o.x = c0.x * be; o.y = c0.y * be; o.z = c0.z * be; o.w = c0.w * be;
    lctx[w][lane] = o;
    o.x = c1.x * be; o.y = c1.y * be; o.z = c1.z * be; o.w = c1.w * be;
    lctx[w][lane + 64] = o;
    o.x = c2.x * be; o.y = c2.y * be; o.z = c2.z * be; o.w = c2.w * be;
    lctx[w][lane + 128] = o;
    o.x = c3.x * be; o.y = c3.y * be; o.z = c3.z * be; o.w = c3.w * be;
    lctx[w][lane + 192] = o;
    __syncthreads();
    int tid = threadIdx.x;
    float4 a0 = lctx[0][tid], a1 = lctx[1][tid], a2 = lctx[2][tid], a3 = lctx[3][tid];
    float4 r;
    r.x = (a0.x + a1.x) + (a2.x + a3.x);
    r.y = (a0.y + a1.y) + (a2.y + a3.y);
    r.z = (a0.z + a1.z) + (a2.z + a3.z);
    r.w = (a0.w + a1.w) + (a2.w + a3.w);
    ((float4*)g_cp)[((size_t)tc * BB + b) * (ENCD / 4) + tid] = r;
    if (tid == 0) { g_m[tc * BB + b] = M; g_s[tc * BB + b] = S; }
}

// ---------------------------------------------------------------------------
// K2: combine 32 chunk partials per batch with global max/sum correction.
// grid (32 b, 4 dq) = 128 blocks; thread owns one scalar d of the context.
// ---------------------------------------------------------------------------
__global__ __launch_bounds__(256) void k_combine() {
    __shared__ float wgt[NTT];
    int b = blockIdx.x, dq = blockIdx.y, tid = threadIdx.x;
    float M = -1e30f;
#pragma unroll
    for (int tt = 0; tt < NTT; tt++) M = fmaxf(M, g_m[tt * BB + b]);
    float S = 0.f;
#pragma unroll
    for (int tt = 0; tt < NTT; tt++) S += g_s[tt * BB + b] * __expf(g_m[tt * BB + b] - M);
    if (tid < NTT) wgt[tid] = __expf(g_m[tid * BB + b] - M) * __fdividef(1.f, S);
    __syncthreads();
    int d = dq * 256 + tid;
    float acc = 0.f;
#pragma unroll 8
    for (int tt = 0; tt < NTT; tt++)
        acc = fmaf(wgt[tt], g_cp[((size_t)tt * BB + b) * ENCD + d], acc);
    g_ctx[b * ENCD + d] = acc;
}

// ---------------------------------------------------------------------------
// K3: z partials. grid 272 = 16 jt x 17 kc (KCH=128; last chunk 80 rows).
// x staged in LDS for all 32 batches; weight loads batched 8-wide.
// KCH=128 halves the g_zp round-trip vs KCH=64 (35.6 -> 17.8 MB).
// ---------------------------------------------------------------------------
__global__ __launch_bounds__(256) void k_zmm(const float* __restrict__ pm,
                                             const float* __restrict__ h,
                                             const float* __restrict__ kern,
                                             const float* __restrict__ reck) {
    __shared__ float xs[KCH * 32];
    int jt = blockIdx.x & 15, kc = blockIdx.x >> 4;
    int k0 = kc * KCH;
    int kcount = min(KCH, KTOT - k0);   // 128 or 80, both divisible by 8
    int tid = threadIdx.x;
    for (int idx = tid; idx < kcount * 32; idx += 256) {
        int kk = idx >> 5, b = idx & 31;
        int k = k0 + kk;
        float v;
        if (k < MELD)             v = pm[b * MELD + k];
        else if (k < MELD + ENCD) v = g_ctx[b * ENCD + (k - MELD)];
        else                      v = h[b * DECD + (k - MELD - ENCD)];
        xs[idx] = v;
    }
    __syncthreads();
    int j = jt * 256 + tid;
    float acc[32];
#pragma unroll
    for (int b = 0; b < 32; b++) acc[b] = 0.f;
    for (int kk0 = 0; kk0 < kcount; kk0 += 8) {
        float w[8];
#pragma unroll
        for (int i = 0; i < 8; i++) {
            int k = k0 + kk0 + i;
            w[i] = (k < MELD + ENCD) ? kern[(size_t)k * NZ + j]
                                     : reck[(size_t)(k - MELD - ENCD) * NZ + j];
        }
#pragma unroll
        for (int i = 0; i < 8; i++) {
            const float* xr = xs + (kk0 + i) * 32;
#pragma unroll
            for (int b = 0; b < 32; b++) acc[b] = fmaf(xr[b], w[i], acc[b]);
        }
    }
#pragma unroll
    for (int b = 0; b < 32; b++) g_zp[((size_t)kc * BB + b) * NZ + j] = acc[b];
}

// ---------------------------------------------------------------------------
// K4: sum z partials + bias, gates -> h_new/c_new (fp32 out).
// grid 512 = 32 b x 16 jt (j-tile 64); kc-sum (17 chunks) split 5/4/4/4
// across thread groups, LDS reduce. out: mel[0,2560) h[2560,35328) c[35328,..)
// ---------------------------------------------------------------------------
__global__ __launch_bounds__(256) void k_gates(const float* __restrict__ bias,
                                               const float* __restrict__ c,
                                               float* __restrict__ out) {
    __shared__ float sacc[4][4][64];   // [grp][gate][jl]
    int b = blockIdx.x >> 4, jq = blockIdx.x & 15;
    int jl = threadIdx.x & 63, grp = threadIdx.x >> 6;
    int j = jq * 64 + jl;
    // kc ranges per group: 5,4,4,4  (KC=17)
    int kc0 = (grp == 0) ? 0 : grp * 4 + 1;
    int kc1 = grp * 4 + 5;
    float zi = 0.f, zf = 0.f, zg = 0.f, zo = 0.f;
    for (int kc = kc0; kc < kc1; kc++) {
        const float* zp = g_zp + ((size_t)kc * BB + b) * NZ;
        zi += zp[j];
        zf += zp[1024 + j];
        zg += zp[2048 + j];
        zo += zp[3072 + j];
    }
    sacc[grp][0][jl] = zi; sacc[grp][1][jl] = zf;
    sacc[grp][2][jl] = zg; sacc[grp][3][jl] = zo;
    __syncthreads();
    if (grp == 0) {
        zi = sacc[0][0][jl] + sacc[1][0][jl] + sacc[2][0][jl] + sacc[3][0][jl] + bias[j];
        zf = sacc[0][1][jl] + sacc[1][1][jl] + sacc[2][1][jl] + sacc[3][1][jl] + bias[1024 + j];
        zg = sacc[0][2][jl] + sacc[1][2][jl] + sacc[2][2][jl] + sacc[3][2][jl] + bias[2048 + j];
        zo = sacc[0][3][jl] + sacc[1][3][jl] + sacc[2][3][jl] + sacc[3][3][jl] + bias[3072 + j];
        int idx = b * 1024 + j;
        float cn = sigmoid_fast(zf) * c[idx] + sigmoid_fast(zi) * tanh_fast(zg);
        float hn = sigmoid_fast(zo) * tanh_fast(cn);
        g_hn[idx] = hn;
        out[2560 + idx] = hn;
        out[35328 + idx] = cn;
    }
}

// ---------------------------------------------------------------------------
// K5: mel[b,m] = h_new[b,:] @ proj_w[:,m] + proj_b[m]
// grid 32; 160 active threads = 80 m x 2 d-halves, LDS combine.
// ---------------------------------------------------------------------------
__global__ __launch_bounds__(256) void k_proj(const float* __restrict__ pw,
                                              const float* __restrict__ pb,
                                              float* __restrict__ out) {
    __shared__ float lh[1024];
    __shared__ float pacc[2][MELD];
    int b = blockIdx.x, tid = threadIdx.x;
    for (int i = tid; i < 1024; i += 256) lh[i] = g_hn[b * 1024 + i];
    __syncthreads();
    int m = tid & 127;
    int g = tid >> 7;
    if (m < MELD) {
        float acc = 0.f;
        int d0 = g * 512;
#pragma unroll 8
        for (int d = d0; d < d0 + 512; d++) acc = fmaf(lh[d], pw[d * MELD + m], acc);
        pacc[g][m] = acc;
    }
    __syncthreads();
    if (tid < MELD) out[b * MELD + tid] = pacc[0][tid] + pacc[1][tid] + pb[tid];
}

extern "C" void kernel_launch(void* const* d_in, const int* in_sizes, int n_in,
                              void* d_out, int out_size, void* d_ws, size_t ws_size,
                              hipStream_t stream) {
    const float* pm   = (const float*)d_in[0];   // prev_mel_frame [32,80]
    const float* enc  = (const float*)d_in[1];   // encoder_outputs [32,1024,1024]
    const float* h    = (const float*)d_in[2];   // h [32,1024]
    const float* c    = (const float*)d_in[3];   // c [32,1024]
    const float* asc  = (const float*)d_in[4];   // attn_scale [1024]
    const float* kern = (const float*)d_in[5];   // kernel [1104,4096]
    const float* reck = (const float*)d_in[6];   // rec_kernel [1024,4096]
    const float* bias = (const float*)d_in[7];   // bias [4096]
    const float* pw   = (const float*)d_in[8];   // proj_w [1024,80]
    const float* pb   = (const float*)d_in[9];   // proj_b [80]
    float* out = (float*)d_out;                  // fp32: mel | h_new | c_new

    k_attn   <<<dim3(32, NTT), 256, 0, stream>>>(enc, h, asc);
    k_combine<<<dim3(32, 4), 256, 0, stream>>>();
    k_zmm    <<<272, 256, 0, stream>>>(pm, h, kern, reck);
    k_gates  <<<512, 256, 0, stream>>>(bias, c, out);
    k_proj   <<<32, 256, 0, stream>>>(pw, pb, out);
}

// Round 3
// 296.757 us; speedup vs baseline: 1.0558x; 1.0341x over previous
//
#include <hip/hip_runtime.h>

#define BB 32
#define TT 1024
#define ENCD 1024
#define DECD 1024
#define MELD 80
#define KTOT (MELD + ENCD + DECD)   // 2128
#define NZ (4 * DECD)               // 4096
#define KCH 128                     // k-rows per zmm chunk
#define KC 17                       // ceil(2128/128); last chunk = 80 rows
#define NTT 32                      // context t-chunks (32 rows each)
#define QR 8                        // rows staged per attn phase (32 KB LDS)

// ---- static device scratch ----
__device__ float g_cp[NTT * BB * ENCD];  // context partials [tt][b][d] (4 MB)
__device__ float g_m[NTT * BB];          // per-chunk max
__device__ float g_s[NTT * BB];          // per-chunk exp-sum (at that max)
__device__ float g_ctx[BB * ENCD];
__device__ float g_zp[KC * BB * NZ];     // z partials [kc][b][j] (8.9 MB)
__device__ float g_hn[BB * DECD];

__device__ __forceinline__ float tanh_fast(float x) {
    // 1 - 2/(e+1): exact +-1 limits (rcp(inf)=0)
    return 1.f - __fdividef(2.f, __expf(2.f * x) + 1.f);
}
__device__ __forceinline__ float sigmoid_fast(float x) {
    return __fdividef(1.f, 1.f + __expf(-x));
}

// ---------------------------------------------------------------------------
// K1: one-pass attention, restructured to remove the per-row serial chain.
// grid (b=32, tc=32) = 1024 blocks (4/CU via 32KB LDS), 256 thr = 4 waves.
// 4 phases of QR=8 rows:
//   A: wave w stages rows {2w,2w+1} to LDS + computes their scores
//      (branch-free k_scores pattern: loads pipeline freely, no carried state)
//   B: exact softmax over the 8 staged scores (block-uniform scalars),
//      ctx[4] += sum_r exp(sc_r - M) * es[r][4*tid] from LDS (b128,
//      conflict-free), block-uniform max-correction between phases.
// No online per-row rescale, no shuffle/exp on the consume path.
// ---------------------------------------------------------------------------
__global__ __launch_bounds__(256, 4) void k_attn(const float* __restrict__ enc,
                                                 const float* __restrict__ hst,
                                                 const float* __restrict__ scale) {
    __shared__ float es[QR][ENCD];   // 32 KB
    __shared__ float ssc[QR];
    int b = blockIdx.x, tc = blockIdx.y;
    int tid = threadIdx.x, w = tid >> 6, lane = tid & 63;
    const float4* hp = (const float4*)(hst + (size_t)b * DECD);
    const float4* sp = (const float4*)scale;
    float4 hr0 = hp[lane], hr1 = hp[lane + 64], hr2 = hp[lane + 128], hr3 = hp[lane + 192];
    float4 sr0 = sp[lane], sr1 = sp[lane + 64], sr2 = sp[lane + 128], sr3 = sp[lane + 192];

    float M = -1e30f, S = 0.f;
    float cx = 0.f, cy = 0.f, cz = 0.f, cw = 0.f;
    const float4* ebase = (const float4*)(enc + ((size_t)b * TT + tc * 32) * ENCD);

    for (int q = 0; q < 4; q++) {
#pragma unroll
        for (int rr = 0; rr < 2; rr++) {
            int r = w * 2 + rr;                       // 0..7 within phase
            const float4* ep = ebase + (size_t)(q * QR + r) * (ENCD / 4) + lane;
            float4 e0 = ep[0], e1 = ep[64], e2 = ep[128], e3 = ep[192];
            float sc = 0.f;
            sc = fmaf(sr0.x, tanh_fast(hr0.x + e0.x), sc);
            sc = fmaf(sr0.y, tanh_fast(hr0.y + e0.y), sc);
            sc = fmaf(sr0.z, tanh_fast(hr0.z + e0.z), sc);
            sc = fmaf(sr0.w, tanh_fast(hr0.w + e0.w), sc);
            sc = fmaf(sr1.x, tanh_fast(hr1.x + e1.x), sc);
            sc = fmaf(sr1.y, tanh_fast(hr1.y + e1.y), sc);
            sc = fmaf(sr1.z, tanh_fast(hr1.z + e1.z), sc);
            sc = fmaf(sr1.w, tanh_fast(hr1.w + e1.w), sc);
            sc = fmaf(sr2.x, tanh_fast(hr2.x + e2.x), sc);
            sc = fmaf(sr2.y, tanh_fast(hr2.y + e2.y), sc);
            sc = fmaf(sr2.z, tanh_fast(hr2.z + e2.z), sc);
            sc = fmaf(sr2.w, tanh_fast(hr2.w + e2.w), sc);
            sc = fmaf(sr3.x, tanh_fast(hr3.x + e3.x), sc);
            sc = fmaf(sr3.y, tanh_fast(hr3.y + e3.y), sc);
            sc = fmaf(sr3.z, tanh_fast(hr3.z + e3.z), sc);
            sc = fmaf(sr3.w, tanh_fast(hr3.w + e3.w), sc);
#pragma unroll
            for (int off = 32; off; off >>= 1) sc += __shfl_xor(sc, off, 64);
            float4* esr = (float4*)&es[r][0];
            esr[lane] = e0; esr[lane + 64] = e1;
            esr[lane + 128] = e2; esr[lane + 192] = e3;
            if (lane == 0) ssc[r] = sc;
        }
        __syncthreads();
        // exact softmax over this phase's 8 scores (block-uniform)
        float s0 = ssc[0], s1 = ssc[1], s2 = ssc[2], s3 = ssc[3];
        float s4 = ssc[4], s5 = ssc[5], s6 = ssc[6], s7 = ssc[7];
        float mq = fmaxf(fmaxf(fmaxf(s0, s1), fmaxf(s2, s3)),
                         fmaxf(fmaxf(s4, s5), fmaxf(s6, s7)));
        float Mn = fmaxf(M, mq);
        float alO = __expf(M - Mn);          // first phase: exp(-inf) = 0
        float w0 = __expf(s0 - Mn), w1 = __expf(s1 - Mn);
        float w2 = __expf(s2 - Mn), w3 = __expf(s3 - Mn);
        float w4 = __expf(s4 - Mn), w5 = __expf(s5 - Mn);
        float w6 = __expf(s6 - Mn), w7 = __expf(s7 - Mn);
        float Sq = ((w0 + w1) + (w2 + w3)) + ((w4 + w5) + (w6 + w7));
        S = fmaf(S, alO, Sq);
        M = Mn;
        cx *= alO; cy *= alO; cz *= alO; cw *= alO;
        const float4* col = (const float4*)&es[0][0] + tid;   // row stride 256 f4
        float wr[QR] = {w0, w1, w2, w3, w4, w5, w6, w7};
#pragma unroll
        for (int r = 0; r < QR; r++) {
            float4 e = col[r * 256];
            cx = fmaf(wr[r], e.x, cx); cy = fmaf(wr[r], e.y, cy);
            cz = fmaf(wr[r], e.z, cz); cw = fmaf(wr[r], e.w, cw);
        }
        __syncthreads();   // before next phase overwrites es
    }
    float4 r4; r4.x = cx; r4.y = cy; r4.z = cz; r4.w = cw;
    ((float4*)g_cp)[((size_t)tc * BB + b) * (ENCD / 4) + tid] = r4;
    if (tid == 0) { g_m[tc * BB + b] = M; g_s[tc * BB + b] = S; }
}

// ---------------------------------------------------------------------------
// K2: combine 32 chunk partials per batch with global max/sum correction.
// grid (32 b, 4 dq) = 128 blocks; thread owns one scalar d of the context.
// ---------------------------------------------------------------------------
__global__ __launch_bounds__(256) void k_combine() {
    __shared__ float wgt[NTT];
    int b = blockIdx.x, dq = blockIdx.y, tid = threadIdx.x;
    float M = -1e30f;
#pragma unroll
    for (int tt = 0; tt < NTT; tt++) M = fmaxf(M, g_m[tt * BB + b]);
    float S = 0.f;
#pragma unroll
    for (int tt = 0; tt < NTT; tt++) S += g_s[tt * BB + b] * __expf(g_m[tt * BB + b] - M);
    if (tid < NTT) wgt[tid] = __expf(g_m[tid * BB + b] - M) * __fdividef(1.f, S);
    __syncthreads();
    int d = dq * 256 + tid;
    float acc = 0.f;
#pragma unroll 8
    for (int tt = 0; tt < NTT; tt++)
        acc = fmaf(wgt[tt], g_cp[((size_t)tt * BB + b) * ENCD + d], acc);
    g_ctx[b * ENCD + d] = acc;
}

// ---------------------------------------------------------------------------
// K3: z partials. grid 272 = 16 jt x 17 kc (KCH=128; last chunk 80 rows).
// x staged in LDS for all 32 batches; weight loads batched 8-wide.
// ---------------------------------------------------------------------------
__global__ __launch_bounds__(256) void k_zmm(const float* __restrict__ pm,
                                             const float* __restrict__ h,
                                             const float* __restrict__ kern,
                                             const float* __restrict__ reck) {
    __shared__ float xs[KCH * 32];
    int jt = blockIdx.x & 15, kc = blockIdx.x >> 4;
    int k0 = kc * KCH;
    int kcount = min(KCH, KTOT - k0);   // 128 or 80, both divisible by 8
    int tid = threadIdx.x;
    for (int idx = tid; idx < kcount * 32; idx += 256) {
        int kk = idx >> 5, b = idx & 31;
        int k = k0 + kk;
        float v;
        if (k < MELD)             v = pm[b * MELD + k];
        else if (k < MELD + ENCD) v = g_ctx[b * ENCD + (k - MELD)];
        else                      v = h[b * DECD + (k - MELD - ENCD)];
        xs[idx] = v;
    }
    __syncthreads();
    int j = jt * 256 + tid;
    float acc[32];
#pragma unroll
    for (int b = 0; b < 32; b++) acc[b] = 0.f;
    for (int kk0 = 0; kk0 < kcount; kk0 += 8) {
        float w[8];
#pragma unroll
        for (int i = 0; i < 8; i++) {
            int k = k0 + kk0 + i;
            w[i] = (k < MELD + ENCD) ? kern[(size_t)k * NZ + j]
                                     : reck[(size_t)(k - MELD - ENCD) * NZ + j];
        }
#pragma unroll
        for (int i = 0; i < 8; i++) {
            const float* xr = xs + (kk0 + i) * 32;
#pragma unroll
            for (int b = 0; b < 32; b++) acc[b] = fmaf(xr[b], w[i], acc[b]);
        }
    }
#pragma unroll
    for (int b = 0; b < 32; b++) g_zp[((size_t)kc * BB + b) * NZ + j] = acc[b];
}

// ---------------------------------------------------------------------------
// K4: sum z partials + bias, gates -> h_new/c_new (fp32 out).
// grid 512 = 32 b x 16 jt (j-tile 64); kc-sum (17 chunks) split 5/4/4/4
// across thread groups, LDS reduce. out: mel[0,2560) h[2560,35328) c[35328,..)
// ---------------------------------------------------------------------------
__global__ __launch_bounds__(256) void k_gates(const float* __restrict__ bias,
                                               const float* __restrict__ c,
                                               float* __restrict__ out) {
    __shared__ float sacc[4][4][64];   // [grp][gate][jl]
    int b = blockIdx.x >> 4, jq = blockIdx.x & 15;
    int jl = threadIdx.x & 63, grp = threadIdx.x >> 6;
    int j = jq * 64 + jl;
    // kc ranges per group: 5,4,4,4  (KC=17)
    int kc0 = (grp == 0) ? 0 : grp * 4 + 1;
    int kc1 = grp * 4 + 5;
    float zi = 0.f, zf = 0.f, zg = 0.f, zo = 0.f;
    for (int kc = kc0; kc < kc1; kc++) {
        const float* zp = g_zp + ((size_t)kc * BB + b) * NZ;
        zi += zp[j];
        zf += zp[1024 + j];
        zg += zp[2048 + j];
        zo += zp[3072 + j];
    }
    sacc[grp][0][jl] = zi; sacc[grp][1][jl] = zf;
    sacc[grp][2][jl] = zg; sacc[grp][3][jl] = zo;
    __syncthreads();
    if (grp == 0) {
        zi = sacc[0][0][jl] + sacc[1][0][jl] + sacc[2][0][jl] + sacc[3][0][jl] + bias[j];
        zf = sacc[0][1][jl] + sacc[1][1][jl] + sacc[2][1][jl] + sacc[3][1][jl] + bias[1024 + j];
        zg = sacc[0][2][jl] + sacc[1][2][jl] + sacc[2][2][jl] + sacc[3][2][jl] + bias[2048 + j];
        zo = sacc[0][3][jl] + sacc[1][3][jl] + sacc[2][3][jl] + sacc[3][3][jl] + bias[3072 + j];
        int idx = b * 1024 + j;
        float cn = sigmoid_fast(zf) * c[idx] + sigmoid_fast(zi) * tanh_fast(zg);
        float hn = sigmoid_fast(zo) * tanh_fast(cn);
        g_hn[idx] = hn;
        out[2560 + idx] = hn;
        out[35328 + idx] = cn;
    }
}

// ---------------------------------------------------------------------------
// K5: mel[b,m] = h_new[b,:] @ proj_w[:,m] + proj_b[m]
// grid 32; 160 active threads = 80 m x 2 d-halves, LDS combine.
// ---------------------------------------------------------------------------
__global__ __launch_bounds__(256) void k_proj(const float* __restrict__ pw,
                                              const float* __restrict__ pb,
                                              float* __restrict__ out) {
    __shared__ float lh[1024];
    __shared__ float pacc[2][MELD];
    int b = blockIdx.x, tid = threadIdx.x;
    for (int i = tid; i < 1024; i += 256) lh[i] = g_hn[b * 1024 + i];
    __syncthreads();
    int m = tid & 127;
    int g = tid >> 7;
    if (m < MELD) {
        float acc = 0.f;
        int d0 = g * 512;
#pragma unroll 8
        for (int d = d0; d < d0 + 512; d++) acc = fmaf(lh[d], pw[d * MELD + m], acc);
        pacc[g][m] = acc;
    }
    __syncthreads();
    if (tid < MELD) out[b * MELD + tid] = pacc[0][tid] + pacc[1][tid] + pb[tid];
}

extern "C" void kernel_launch(void* const* d_in, const int* in_sizes, int n_in,
                              void* d_out, int out_size, void* d_ws, size_t ws_size,
                              hipStream_t stream) {
    const float* pm   = (const float*)d_in[0];   // prev_mel_frame [32,80]
    const float* enc  = (const float*)d_in[1];   // encoder_outputs [32,1024,1024]
    const float* h    = (const float*)d_in[2];   // h [32,1024]
    const float* c    = (const float*)d_in[3];   // c [32,1024]
    const float* asc  = (const float*)d_in[4];   // attn_scale [1024]
    const float* kern = (const float*)d_in[5];   // kernel [1104,4096]
    const float* reck = (const float*)d_in[6];   // rec_kernel [1024,4096]
    const float* bias = (const float*)d_in[7];   // bias [4096]
    const float* pw   = (const float*)d_in[8];   // proj_w [1024,80]
    const float* pb   = (const float*)d_in[9];   // proj_b [80]
    float* out = (float*)d_out;                  // fp32: mel | h_new | c_new

    k_attn   <<<dim3(32, NTT), 256, 0, stream>>>(enc, h, asc);
    k_combine<<<dim3(32, 4), 256, 0, stream>>>();
    k_zmm    <<<272, 256, 0, stream>>>(pm, h, kern, reck);
    k_gates  <<<512, 256, 0, stream>>>(bias, c, out);
    k_proj   <<<32, 256, 0, stream>>>(pw, pb, out);
}

// Round 4
// 287.713 us; speedup vs baseline: 1.0890x; 1.0314x over previous
//
#include <hip/hip_runtime.h>

#define BB 32
#define TT 1024
#define ENCD 1024
#define DECD 1024
#define MELD 80
#define KTOT (MELD + ENCD + DECD)   // 2128
#define NZ (4 * DECD)               // 4096
#define KCH 136                     // k-rows per zmm chunk (16 chunks; last = 88)
#define KC 16                       // number of zmm k-chunks
#define NTT 32                      // context t-chunks (32 rows each)
#define QR 8                        // rows staged per attn phase (32 KB LDS)

// ---- static device scratch ----
__device__ float g_cp[NTT * BB * ENCD];  // context partials [tt][b][d] (4 MB)
__device__ float g_m[NTT * BB];          // per-chunk max
__device__ float g_s[NTT * BB];          // per-chunk exp-sum (at that max)
__device__ float g_ctx[BB * ENCD];
__device__ float g_zp[KC * BB * NZ];     // z partials [kc][b][j] (8.4 MB)
__device__ float g_hn[BB * DECD];

__device__ __forceinline__ float tanh_fast(float x) {
    // 1 - 2/(e+1): exact +-1 limits (rcp(inf)=0)
    return 1.f - __fdividef(2.f, __expf(2.f * x) + 1.f);
}
__device__ __forceinline__ float sigmoid_fast(float x) {
    return __fdividef(1.f, 1.f + __expf(-x));
}

// ---------------------------------------------------------------------------
// K1: one-pass attention (unchanged from round 3).
// grid (b=32, tc=32) = 1024 blocks (exactly 4/CU), 256 thr = 4 waves.
// 4 phases of QR=8 rows: stage rows+scores branch-free, exact 8-score
// softmax of block-uniform scalars, LDS-consume with phase max-correction.
// ---------------------------------------------------------------------------
__global__ __launch_bounds__(256, 4) void k_attn(const float* __restrict__ enc,
                                                 const float* __restrict__ hst,
                                                 const float* __restrict__ scale) {
    __shared__ float es[QR][ENCD];   // 32 KB
    __shared__ float ssc[QR];
    int b = blockIdx.x, tc = blockIdx.y;
    int tid = threadIdx.x, w = tid >> 6, lane = tid & 63;
    const float4* hp = (const float4*)(hst + (size_t)b * DECD);
    const float4* sp = (const float4*)scale;
    float4 hr0 = hp[lane], hr1 = hp[lane + 64], hr2 = hp[lane + 128], hr3 = hp[lane + 192];
    float4 sr0 = sp[lane], sr1 = sp[lane + 64], sr2 = sp[lane + 128], sr3 = sp[lane + 192];

    float M = -1e30f, S = 0.f;
    float cx = 0.f, cy = 0.f, cz = 0.f, cw = 0.f;
    const float4* ebase = (const float4*)(enc + ((size_t)b * TT + tc * 32) * ENCD);

    for (int q = 0; q < 4; q++) {
#pragma unroll
        for (int rr = 0; rr < 2; rr++) {
            int r = w * 2 + rr;                       // 0..7 within phase
            const float4* ep = ebase + (size_t)(q * QR + r) * (ENCD / 4) + lane;
            float4 e0 = ep[0], e1 = ep[64], e2 = ep[128], e3 = ep[192];
            float sc = 0.f;
            sc = fmaf(sr0.x, tanh_fast(hr0.x + e0.x), sc);
            sc = fmaf(sr0.y, tanh_fast(hr0.y + e0.y), sc);
            sc = fmaf(sr0.z, tanh_fast(hr0.z + e0.z), sc);
            sc = fmaf(sr0.w, tanh_fast(hr0.w + e0.w), sc);
            sc = fmaf(sr1.x, tanh_fast(hr1.x + e1.x), sc);
            sc = fmaf(sr1.y, tanh_fast(hr1.y + e1.y), sc);
            sc = fmaf(sr1.z, tanh_fast(hr1.z + e1.z), sc);
            sc = fmaf(sr1.w, tanh_fast(hr1.w + e1.w), sc);
            sc = fmaf(sr2.x, tanh_fast(hr2.x + e2.x), sc);
            sc = fmaf(sr2.y, tanh_fast(hr2.y + e2.y), sc);
            sc = fmaf(sr2.z, tanh_fast(hr2.z + e2.z), sc);
            sc = fmaf(sr2.w, tanh_fast(hr2.w + e2.w), sc);
            sc = fmaf(sr3.x, tanh_fast(hr3.x + e3.x), sc);
            sc = fmaf(sr3.y, tanh_fast(hr3.y + e3.y), sc);
            sc = fmaf(sr3.z, tanh_fast(hr3.z + e3.z), sc);
            sc = fmaf(sr3.w, tanh_fast(hr3.w + e3.w), sc);
#pragma unroll
            for (int off = 32; off; off >>= 1) sc += __shfl_xor(sc, off, 64);
            float4* esr = (float4*)&es[r][0];
            esr[lane] = e0; esr[lane + 64] = e1;
            esr[lane + 128] = e2; esr[lane + 192] = e3;
            if (lane == 0) ssc[r] = sc;
        }
        __syncthreads();
        float s0 = ssc[0], s1 = ssc[1], s2 = ssc[2], s3 = ssc[3];
        float s4 = ssc[4], s5 = ssc[5], s6 = ssc[6], s7 = ssc[7];
        float mq = fmaxf(fmaxf(fmaxf(s0, s1), fmaxf(s2, s3)),
                         fmaxf(fmaxf(s4, s5), fmaxf(s6, s7)));
        float Mn = fmaxf(M, mq);
        float alO = __expf(M - Mn);          // first phase: exp(-inf) = 0
        float w0 = __expf(s0 - Mn), w1 = __expf(s1 - Mn);
        float w2 = __expf(s2 - Mn), w3 = __expf(s3 - Mn);
        float w4 = __expf(s4 - Mn), w5 = __expf(s5 - Mn);
        float w6 = __expf(s6 - Mn), w7 = __expf(s7 - Mn);
        float Sq = ((w0 + w1) + (w2 + w3)) + ((w4 + w5) + (w6 + w7));
        S = fmaf(S, alO, Sq);
        M = Mn;
        cx *= alO; cy *= alO; cz *= alO; cw *= alO;
        const float4* col = (const float4*)&es[0][0] + tid;   // row stride 256 f4
        float wr[QR] = {w0, w1, w2, w3, w4, w5, w6, w7};
#pragma unroll
        for (int r = 0; r < QR; r++) {
            float4 e = col[r * 256];
            cx = fmaf(wr[r], e.x, cx); cy = fmaf(wr[r], e.y, cy);
            cz = fmaf(wr[r], e.z, cz); cw = fmaf(wr[r], e.w, cw);
        }
        __syncthreads();   // before next phase overwrites es
    }
    float4 r4; r4.x = cx; r4.y = cy; r4.z = cz; r4.w = cw;
    ((float4*)g_cp)[((size_t)tc * BB + b) * (ENCD / 4) + tid] = r4;
    if (tid == 0) { g_m[tc * BB + b] = M; g_s[tc * BB + b] = S; }
}

// ---------------------------------------------------------------------------
// K2: combine 32 chunk partials per batch with global max/sum correction.
// grid (32 b, 8 dq) = 256 blocks x 128 thr = 1 block/CU; thread owns one d.
// ---------------------------------------------------------------------------
__global__ __launch_bounds__(128) void k_combine() {
    __shared__ float wgt[NTT];
    int b = blockIdx.x, dq = blockIdx.y, tid = threadIdx.x;
    float M = -1e30f;
#pragma unroll
    for (int tt = 0; tt < NTT; tt++) M = fmaxf(M, g_m[tt * BB + b]);
    float S = 0.f;
#pragma unroll
    for (int tt = 0; tt < NTT; tt++) S += g_s[tt * BB + b] * __expf(g_m[tt * BB + b] - M);
    if (tid < NTT) wgt[tid] = __expf(g_m[tid * BB + b] - M) * __fdividef(1.f, S);
    __syncthreads();
    int d = dq * 128 + tid;
    float acc = 0.f;
#pragma unroll 8
    for (int tt = 0; tt < NTT; tt++)
        acc = fmaf(wgt[tt], g_cp[((size_t)tt * BB + b) * ENCD + d], acc);
    g_ctx[b * ENCD + d] = acc;
}

// ---------------------------------------------------------------------------
// K3: z partials. grid 512 = 32 jt (128 j) x 16 kc (KCH=136; last = 88).
// Exactly 2 blocks/CU (no tail), 8 waves/CU for latency hiding.
// 256 thr = 128 j x 2 k-halves (rows 72/64; last chunk 48/40, all /8).
// x staged in LDS for all 32 batches; halves LDS-combined before store.
// ---------------------------------------------------------------------------
__global__ __launch_bounds__(256) void k_zmm(const float* __restrict__ pm,
                                             const float* __restrict__ h,
                                             const float* __restrict__ kern,
                                             const float* __restrict__ reck) {
    __shared__ float xs[KCH * 32];       // 17.4 KB
    __shared__ float sacc[32 * 128];     // 16 KB: khalf-1 partials [b][jl]
    int jt = blockIdx.x & 31, kc = blockIdx.x >> 5;
    int k0 = kc * KCH;
    int kcount = min(KCH, KTOT - k0);    // 136 or 88
    int tid = threadIdx.x;
    for (int idx = tid; idx < kcount * 32; idx += 256) {
        int kk = idx >> 5, b = idx & 31;
        int k = k0 + kk;
        float v;
        if (k < MELD)             v = pm[b * MELD + k];
        else if (k < MELD + ENCD) v = g_ctx[b * ENCD + (k - MELD)];
        else                      v = h[b * DECD + (k - MELD - ENCD)];
        xs[idx] = v;
    }
    __syncthreads();
    int jl = tid & 127, kh = tid >> 7;
    int j = jt * 128 + jl;
    int split = (kcount == KCH) ? 72 : 48;    // both halves divisible by 8
    int kb = kh ? split : 0;
    int ke = kh ? kcount : split;
    float acc[32];
#pragma unroll
    for (int b = 0; b < 32; b++) acc[b] = 0.f;
    for (int kk0 = kb; kk0 < ke; kk0 += 8) {
        float w[8];
#pragma unroll
        for (int i = 0; i < 8; i++) {
            int k = k0 + kk0 + i;
            w[i] = (k < MELD + ENCD) ? kern[(size_t)k * NZ + j]
                                     : reck[(size_t)(k - MELD - ENCD) * NZ + j];
        }
#pragma unroll
        for (int i = 0; i < 8; i++) {
            const float* xr = xs + (kk0 + i) * 32;
#pragma unroll
            for (int b = 0; b < 32; b++) acc[b] = fmaf(xr[b], w[i], acc[b]);
        }
    }
    if (kh) {
#pragma unroll
        for (int b = 0; b < 32; b++) sacc[b * 128 + jl] = acc[b];
    }
    __syncthreads();
    if (!kh) {
#pragma unroll
        for (int b = 0; b < 32; b++)
            g_zp[((size_t)kc * BB + b) * NZ + j] = acc[b] + sacc[b * 128 + jl];
    }
}

// ---------------------------------------------------------------------------
// K4: sum z partials + bias, gates -> h_new/c_new (fp32 out).
// grid 512 = 32 b x 16 jt (j-tile 64); kc-sum (16 chunks) split 4/4/4/4
// across thread groups, LDS reduce. out: mel[0,2560) h[2560,35328) c[35328,..)
// ---------------------------------------------------------------------------
__global__ __launch_bounds__(256) void k_gates(const float* __restrict__ bias,
                                               const float* __restrict__ c,
                                               float* __restrict__ out) {
    __shared__ float sacc[4][4][64];   // [grp][gate][jl]
    int b = blockIdx.x >> 4, jq = blockIdx.x & 15;
    int jl = threadIdx.x & 63, grp = threadIdx.x >> 6;
    int j = jq * 64 + jl;
    int kc0 = grp * 4;
    int kc1 = kc0 + 4;
    float zi = 0.f, zf = 0.f, zg = 0.f, zo = 0.f;
    for (int kc = kc0; kc < kc1; kc++) {
        const float* zp = g_zp + ((size_t)kc * BB + b) * NZ;
        zi += zp[j];
        zf += zp[1024 + j];
        zg += zp[2048 + j];
        zo += zp[3072 + j];
    }
    sacc[grp][0][jl] = zi; sacc[grp][1][jl] = zf;
    sacc[grp][2][jl] = zg; sacc[grp][3][jl] = zo;
    __syncthreads();
    if (grp == 0) {
        zi = sacc[0][0][jl] + sacc[1][0][jl] + sacc[2][0][jl] + sacc[3][0][jl] + bias[j];
        zf = sacc[0][1][jl] + sacc[1][1][jl] + sacc[2][1][jl] + sacc[3][1][jl] + bias[1024 + j];
        zg = sacc[0][2][jl] + sacc[1][2][jl] + sacc[2][2][jl] + sacc[3][2][jl] + bias[2048 + j];
        zo = sacc[0][3][jl] + sacc[1][3][jl] + sacc[2][3][jl] + sacc[3][3][jl] + bias[3072 + j];
        int idx = b * 1024 + j;
        float cn = sigmoid_fast(zf) * c[idx] + sigmoid_fast(zi) * tanh_fast(zg);
        float hn = sigmoid_fast(zo) * tanh_fast(cn);
        g_hn[idx] = hn;
        out[2560 + idx] = hn;
        out[35328 + idx] = cn;
    }
}

// ---------------------------------------------------------------------------
// K5: mel[b,m] = h_new[b,:] @ proj_w[:,m] + proj_b[m]
// grid 32; 160 active threads = 80 m x 2 d-halves, LDS combine.
// ---------------------------------------------------------------------------
__global__ __launch_bounds__(256) void k_proj(const float* __restrict__ pw,
                                              const float* __restrict__ pb,
                                              float* __restrict__ out) {
    __shared__ float lh[1024];
    __shared__ float pacc[2][MELD];
    int b = blockIdx.x, tid = threadIdx.x;
    for (int i = tid; i < 1024; i += 256) lh[i] = g_hn[b * 1024 + i];
    __syncthreads();
    int m = tid & 127;
    int g = tid >> 7;
    if (m < MELD) {
        float acc = 0.f;
        int d0 = g * 512;
#pragma unroll 8
        for (int d = d0; d < d0 + 512; d++) acc = fmaf(lh[d], pw[d * MELD + m], acc);
        pacc[g][m] = acc;
    }
    __syncthreads();
    if (tid < MELD) out[b * MELD + tid] = pacc[0][tid] + pacc[1][tid] + pb[tid];
}

extern "C" void kernel_launch(void* const* d_in, const int* in_sizes, int n_in,
                              void* d_out, int out_size, void* d_ws, size_t ws_size,
                              hipStream_t stream) {
    const float* pm   = (const float*)d_in[0];   // prev_mel_frame [32,80]
    const float* enc  = (const float*)d_in[1];   // encoder_outputs [32,1024,1024]
    const float* h    = (const float*)d_in[2];   // h [32,1024]
    const float* c    = (const float*)d_in[3];   // c [32,1024]
    const float* asc  = (const float*)d_in[4];   // attn_scale [1024]
    const float* kern = (const float*)d_in[5];   // kernel [1104,4096]
    const float* reck = (const float*)d_in[6];   // rec_kernel [1024,4096]
    const float* bias = (const float*)d_in[7];   // bias [4096]
    const float* pw   = (const float*)d_in[8];   // proj_w [1024,80]
    const float* pb   = (const float*)d_in[9];   // proj_b [80]
    float* out = (float*)d_out;                  // fp32: mel | h_new | c_new

    k_attn   <<<dim3(32, NTT), 256, 0, stream>>>(enc, h, asc);
    k_combine<<<dim3(32, 8), 128, 0, stream>>>();
    k_zmm    <<<512, 256, 0, stream>>>(pm, h, kern, reck);
    k_gates  <<<512, 256, 0, stream>>>(bias, c, out);
    k_proj   <<<32, 256, 0, stream>>>(pw, pb, out);
}